// Round 13
// baseline (280.325 us; speedup 1.0000x reference)
//
#include <hip/hip_runtime.h>

typedef __bf16 bf16;
typedef __attribute__((ext_vector_type(8))) __bf16 bf16x8;
typedef __attribute__((ext_vector_type(4))) float f32x4;
typedef __attribute__((ext_vector_type(4))) short s16x4;

#define HDIM 2048

__device__ __forceinline__ void glds16(const void* g, void* l) {
  __builtin_amdgcn_global_load_lds((const __attribute__((address_space(1))) void*)g,
                                   (__attribute__((address_space(3))) void*)l,
                                   16, 0, 0);
}

#define MFMA16(a, b, c) __builtin_amdgcn_mfma_f32_16x16x32_bf16(a, b, c, 0, 0, 0)

// fp32 -> bf16 bulk convert: grid (1024, 5). BW-bound (~6 TB/s), done.
__global__ __launch_bounds__(256) void cvt5(
    const float* __restrict__ s0, const float* __restrict__ s1,
    const float* __restrict__ s2, const float* __restrict__ s3,
    const float* __restrict__ s4,
    bf16* __restrict__ d0, bf16* __restrict__ d1, bf16* __restrict__ d2,
    bf16* __restrict__ d3, bf16* __restrict__ d4) {
  const float* s; bf16* d;
  switch (blockIdx.y) {
    case 0: s = s0; d = d0; break;
    case 1: s = s1; d = d1; break;
    case 2: s = s2; d = d2; break;
    case 3: s = s3; d = d3; break;
    default: s = s4; d = d4; break;
  }
  const size_t base = (size_t)blockIdx.x * 4096 + (threadIdx.x << 2);
  for (int i = 0; i < 4; i++) {
    const float4 v = *(const float4*)(s + base + i * 1024);
    union { bf16 h[4]; s16x4 s4v; } u;
    u.h[0] = (bf16)v.x; u.h[1] = (bf16)v.y; u.h[2] = (bf16)v.z; u.h[3] = (bf16)v.w;
    *(s16x4*)(d + base + i * 1024) = u.s4v;
  }
}

// acc[4][4] = A[rowBase:+128, :] @ B[colBase:+128, :]^T, bf16 row-major.
// v14 form (m97 structure: glds16 width-16, BK=32, 4 waves 2x2) — the
// measured local optimum of this family: v15 (BK=64, fewer barrier
// domains), v16 (768-thread fusion, one barrier domain), v17 (XCD swizzle,
// FETCH 45->102MB) all regressed with constant absolute MFMA/VALU cycles.
// The hiding mechanism is 3 co-resident blocks with INDEPENDENT barrier
// domains at different loop phases; default x-major dispatch already has
// near-ideal L2 behavior (45MB fetch vs 32MB ideal).
__device__ __forceinline__ void gemm128_core(const bf16* __restrict__ A,
                                             const bf16* __restrict__ B,
                                             int rowBase, int colBase,
                                             f32x4 acc[4][4],
                                             bf16* ldsA, bf16* ldsB) {
  const int t = threadIdx.x;
  const int w = t >> 6, l = t & 63;
  const int wr = (w >> 1) << 6, wc = (w & 1) << 6;
  const int lr = l & 15, lq = l >> 4;

  for (int mi = 0; mi < 4; mi++)
    for (int ni = 0; ni < 4; ni++)
      for (int r = 0; r < 4; r++) acc[mi][ni][r] = 0.f;

  const int sRow = (w << 4) + (l >> 2);
  const int sCol = (l & 3) << 3;
  const bf16* gA = A + (size_t)(rowBase + sRow) * HDIM + sCol;
  const bf16* gB = B + (size_t)(colBase + sRow) * HDIM + sCol;
  bf16* lA = ldsA + (w << 9);
  bf16* lB = ldsB + (w << 9);

  for (int k0 = 0; k0 < HDIM; k0 += 32) {
    glds16(gA, lA);
    glds16(gA + (size_t)64 * HDIM, lA + 2048);
    glds16(gB, lB);
    glds16(gB + (size_t)64 * HDIM, lB + 2048);
    gA += 32; gB += 32;
    __syncthreads();

    bf16x8 af[4], bfr[4];
    for (int mi = 0; mi < 4; mi++)
      af[mi] = *(const bf16x8*)&ldsA[(wr + mi * 16 + lr) * 32 + lq * 8];
    for (int ni = 0; ni < 4; ni++)
      bfr[ni] = *(const bf16x8*)&ldsB[(wc + ni * 16 + lr) * 32 + lq * 8];
    for (int mi = 0; mi < 4; mi++)
      for (int ni = 0; ni < 4; ni++)
        acc[mi][ni] = MFMA16(af[mi], bfr[ni], acc[mi][ni]);
    __syncthreads();
  }
}

// z=0: q = hs@Wq^T (normal [B,H])
// z=1: Kf = hs@Wk^T re-tiled MFMA-B-frag-major (verified r4)
// z=2: Vf likewise. v18: plain blockIdx mapping restored (v17 swizzle
// reverted — FETCH_SIZE doubled, qkv +5.4us).
__global__ __launch_bounds__(256) void qkv_gemm(
    const bf16* __restrict__ hs, const bf16* __restrict__ Wq,
    const bf16* __restrict__ Wk, const bf16* __restrict__ Wv,
    bf16* __restrict__ qb, bf16* __restrict__ Kf, bf16* __restrict__ Vf) {
  __shared__ bf16 ldsA[128 * 32];
  __shared__ bf16 ldsB[128 * 32];
  const int z = blockIdx.z;
  const bf16* W = (z == 0) ? Wq : (z == 1) ? Wk : Wv;
  const int rowBase = blockIdx.y << 7, colBase = blockIdx.x << 7;
  f32x4 acc[4][4];
  gemm128_core(hs, W, rowBase, colBase, acc, ldsA, ldsB);

  const int t = threadIdx.x;
  const int w = t >> 6, l = t & 63;
  const int wr = (w >> 1) << 6, wc = (w & 1) << 6;
  const int lr = l & 15, lq = l >> 4;

  if (z == 0) {
    for (int mi = 0; mi < 4; mi++)
      for (int ni = 0; ni < 4; ni++) {
        const int col = colBase + wc + ni * 16 + lr;
        const int row0 = rowBase + wr + mi * 16 + lq * 4;
        for (int r = 0; r < 4; r++)
          qb[(size_t)(row0 + r) * HDIM + col] = (bf16)acc[mi][ni][r];
      }
  } else if (z == 1) {
    for (int mi = 0; mi < 4; mi++)
      for (int ni = 0; ni < 4; ni++) {
        const int dim = colBase + wc + ni * 16 + lr;
        const int hh = dim >> 7, ks = (dim >> 5) & 3, kh = (dim >> 3) & 3, j = dim & 7;
        const int row0 = rowBase + wr + mi * 16 + lq * 4;
        for (int r = 0; r < 4; r++) {
          const int key = row0 + r;
          const int kbk = key >> 7, kni = (key >> 4) & 7, kl = key & 15;
          Kf[(((size_t)hh * 16 + kbk) * 32 + kni * 4 + ks) * 512 +
             (kh * 16 + kl) * 8 + j] = (bf16)acc[mi][ni][r];
        }
      }
  } else {
    for (int mi = 0; mi < 4; mi++)
      for (int ni = 0; ni < 4; ni++) {
        const int dim = colBase + wc + ni * 16 + lr;
        const int hh = dim >> 7, vni = (dim >> 4) & 7, ll = dim & 15;
        const int row0 = rowBase + wr + mi * 16 + lq * 4;
        const int kbk = row0 >> 7, ks = (row0 >> 5) & 3, lh = (row0 >> 3) & 3;
        const int j0 = row0 & 7;  // r=0..3 contiguous in j
        union { bf16 h4[4]; s16x4 v; } u;
        for (int r = 0; r < 4; r++) u.h4[r] = (bf16)acc[mi][ni][r];
        *(s16x4*)&Vf[(((size_t)hh * 16 + kbk) * 32 + vni * 4 + ks) * 512 +
                     (lh * 16 + ll) * 8 + j0] = u.v;
      }
  }
}

// Flash attention v18 = v14 (passed, <64.6us) + T5 s_setprio around MFMA
// clusters (kept from v17: total-delta accounting shows attn absorbed ~4us
// while qkv regressed — consistent with m191's +4-7% where waves have
// phase diversity; NOT applied to the lockstep GEMMs per m190).
//  * 8-wave 512-thread block, grid (8 qt x 16 h x 2 kk) = 256 blocks.
//  * Double-buffered K AND V via glds16, single-barrier m97 pattern;
//    8 DMAs/wave/tile drained at the next barrier (depth <=8).
//  * 32 rows/wave; s[2][4] scoped per 64-key half; ~210 unified regs.
//  * LDS 160KB; 0-conflict P swizzle; kk-split partial O/l + combine.
__global__ __launch_bounds__(512, 2) void attn_kernel(
    const bf16* __restrict__ qb, const bf16* __restrict__ Kf,
    const bf16* __restrict__ Vf, const unsigned char* __restrict__ amask,
    float* __restrict__ Of, float* __restrict__ lsumBuf) {
  __shared__ bf16 Kl[2][32 * 512];  // 64KB
  __shared__ bf16 Vl[2][32 * 512];  // 64KB
  __shared__ bf16 Pl[8 * 32 * 64];  // 32KB (4KB/wave: 32 rows x 64 keys)

  const int qt = blockIdx.x, h = blockIdx.y, kk = blockIdx.z;
  const int t = threadIdx.x, w = t >> 6, l = t & 63;
  const int lr = l & 15, lq = l >> 4;
  bf16* Pw = Pl + (w << 11);  // 2048 elems per wave

  // Q A-frags (once): rows qt*256 + w*32 + mi*16 + lr, dims h*128 + ks*32 + lq*8
  bf16x8 aq[2][4];
  for (int mi = 0; mi < 2; mi++)
    for (int ks = 0; ks < 4; ks++)
      aq[mi][ks] = *(const bf16x8*)&qb[(size_t)(qt * 256 + w * 32 + mi * 16 + lr) * HDIM +
                                       h * 128 + ks * 32 + lq * 8];

  f32x4 o[2][8];
  for (int mi = 0; mi < 2; mi++)
    for (int ni = 0; ni < 8; ni++)
      for (int r = 0; r < 4; r++) o[mi][ni][r] = 0.f;
  float lsum[2][4];
  for (int mi = 0; mi < 2; mi++)
    for (int r = 0; r < 4; r++) lsum[mi][r] = 0.f;

  // exp2(s * c): c = 1/sqrt(128) * log2(e)
  const float c = 0.08838834764831845f * 1.4426950408889634f;

  const size_t headOff = (size_t)h * 16 * 32 * 512;
  // diag 128-key tile for this wave's 32 rows (wave-uniform)
  const int diagTile = qt * 2 + (w >> 2);

  // --- prologue: stage tile kk*8 into buf 0 (4 K + 4 V DMAs per wave) ---
  {
    const size_t t0 = headOff + (size_t)(kk * 8) * 32 * 512;
    for (int i = 0; i < 4; i++) {
      const int frag = i * 8 + w;
      glds16(Kf + t0 + frag * 512 + l * 8, &Kl[0][frag * 512]);
    }
    for (int i = 0; i < 4; i++) {
      const int frag = i * 8 + w;
      glds16(Vf + t0 + frag * 512 + l * 8, &Vl[0][frag * 512]);
    }
  }

  for (int tt = 0; tt < 8; tt++) {
    const int kbk = kk * 8 + tt;
    const int buf = tt & 1;

    // barrier: drains tile-t DMAs; all waves past tile t-1's reads of
    // buf^1 -> safe to refill it.
    __syncthreads();

    if (tt < 7) {
      const size_t tN = headOff + (size_t)(kbk + 1) * 32 * 512;
      for (int i = 0; i < 4; i++) {
        const int frag = i * 8 + w;
        glds16(Kf + tN + frag * 512 + l * 8, &Kl[buf ^ 1][frag * 512]);
      }
      for (int i = 0; i < 4; i++) {
        const int frag = i * 8 + w;
        glds16(Vf + tN + frag * 512 + l * 8, &Vl[buf ^ 1][frag * 512]);
      }
    }

    for (int half = 0; half < 2; half++) {
      // --- S = Q @ K^T for this 64-key half (s scoped -> dies per half) ---
      f32x4 s[2][4];
      for (int mi = 0; mi < 2; mi++)
        for (int ni = 0; ni < 4; ni++)
          for (int r = 0; r < 4; r++) s[mi][ni][r] = 0.f;
      __builtin_amdgcn_s_setprio(1);
      for (int ks = 0; ks < 4; ks++) {
        bf16x8 bk[4];
        for (int ni = 0; ni < 4; ni++)
          bk[ni] = *(const bf16x8*)&Kl[buf][((half * 4 + ni) * 4 + ks) * 512 + l * 8];
        for (int ni = 0; ni < 4; ni++) {
          s[0][ni] = MFMA16(aq[0][ks], bk[ni], s[0][ni]);
          s[1][ni] = MFMA16(aq[1][ks], bk[ni], s[1][ni]);
        }
      }
      __builtin_amdgcn_s_setprio(0);

      // --- softmax: additive mask; diag tile uniform per wave ---
      float am[4];
      for (int ni = 0; ni < 4; ni++)
        am[ni] = amask[kbk * 128 + half * 64 + ni * 16 + lr] ? 0.f : -1e30f;
      if (kbk == diagTile) {
        for (int mi = 0; mi < 2; mi++)
          for (int ni = 0; ni < 4; ni++) {
            const int colL = half * 64 + ni * 16 + lr;
            for (int r = 0; r < 4; r++) {
              const int rowL = (w & 3) * 32 + mi * 16 + lq * 4 + r;
              float p = __builtin_exp2f(s[mi][ni][r] * c + am[ni]);
              if (colL == rowL) p = 0.f;
              s[mi][ni][r] = p;
              lsum[mi][r] += p;
            }
          }
      } else {
        for (int mi = 0; mi < 2; mi++)
          for (int ni = 0; ni < 4; ni++)
            for (int r = 0; r < 4; r++) {
              const float p = __builtin_exp2f(s[mi][ni][r] * c + am[ni]);
              s[mi][ni][r] = p;
              lsum[mi][r] += p;
            }
      }

      // --- P write (0-conflict swizzle, 64-key rows; v10/v12-verified) ---
      for (int mi = 0; mi < 2; mi++)
        for (int ni = 0; ni < 4; ni++)
          for (int r = 0; r < 4; r++) {
            const int rl = lq * 4 + r;
            Pw[(mi * 16 + rl) * 64 + (((ni * 2 + (lr >> 3)) ^ (rl & 7)) << 3) +
               (lr & 7)] = (bf16)s[mi][ni][r];
          }

      // --- PV for this half: V k-slices half*2, half*2+1 ---
      __builtin_amdgcn_s_setprio(1);
      for (int ksp = 0; ksp < 2; ksp++) {
        bf16x8 bv[8];
        for (int ni = 0; ni < 8; ni++)
          bv[ni] = *(const bf16x8*)&Vl[buf][(ni * 4 + half * 2 + ksp) * 512 + l * 8];
        const int rchunk = ((ksp * 4 + lq) ^ (lr & 7)) << 3;
        const bf16x8 ap0 = *(const bf16x8*)&Pw[lr * 64 + rchunk];
        const bf16x8 ap1 = *(const bf16x8*)&Pw[(16 + lr) * 64 + rchunk];
        for (int ni = 0; ni < 8; ni++) {
          o[0][ni] = MFMA16(ap0, bv[ni], o[0][ni]);
          o[1][ni] = MFMA16(ap1, bv[ni], o[1][ni]);
        }
      }
      __builtin_amdgcn_s_setprio(0);
    }
  }

  // --- per-wave l reduction: butterfly over the 16 key-lanes ---
  for (int mi = 0; mi < 2; mi++)
    for (int r = 0; r < 4; r++)
      for (int off = 1; off < 16; off <<= 1)
        lsum[mi][r] += __shfl_xor(lsum[mi][r], off);

  // --- epilogue: write f32 partial O and partial l (no division here) ---
  const size_t obase = (size_t)kk * ((size_t)HDIM * HDIM);
  for (int mi = 0; mi < 2; mi++)
    for (int ni = 0; ni < 8; ni++)
      for (int r = 0; r < 4; r++) {
        const int row = qt * 256 + w * 32 + mi * 16 + lq * 4 + r;
        const int col = h * 128 + ni * 16 + lr;
        Of[obase + (size_t)row * HDIM + col] = o[mi][ni][r];
      }
  if (lr == 0)
    for (int mi = 0; mi < 2; mi++)
      for (int r = 0; r < 4; r++) {
        const int row = qt * 256 + w * 32 + mi * 16 + lq * 4 + r;
        lsumBuf[((size_t)kk * 16 + h) * 2048 + row] = lsum[mi][r];
      }
}

// ctx = bf16( (O0+O1) / (l0+l1) ), fully-masked rows -> 0.  Grid 2048x256,
// 8 elems/thread (one row per block). Of traffic is L2/L3-resident.
__global__ __launch_bounds__(256) void combine_kernel(
    const float* __restrict__ Of, const float* __restrict__ lsumBuf,
    bf16* __restrict__ ctx) {
  const size_t base = (size_t)blockIdx.x * 2048 + ((size_t)threadIdx.x << 3);
  const int row = (int)(base >> 11);
  const int h = ((int)base & 2047) >> 7;
  const float lt = lsumBuf[h * 2048 + row] + lsumBuf[(16 + h) * 2048 + row];
  const float linv = (lt > 0.f) ? 1.f / lt : 0.f;
  const float* p0 = Of + base;
  const float* p1 = Of + (size_t)4194304 + base;
  const float4 a0 = *(const float4*)p0;
  const float4 a1 = *(const float4*)(p0 + 4);
  const float4 b0 = *(const float4*)p1;
  const float4 b1 = *(const float4*)(p1 + 4);
  union { bf16 hh[8]; s16x4 v[2]; } u;
  u.hh[0] = (bf16)((a0.x + b0.x) * linv);
  u.hh[1] = (bf16)((a0.y + b0.y) * linv);
  u.hh[2] = (bf16)((a0.z + b0.z) * linv);
  u.hh[3] = (bf16)((a0.w + b0.w) * linv);
  u.hh[4] = (bf16)((a1.x + b1.x) * linv);
  u.hh[5] = (bf16)((a1.y + b1.y) * linv);
  u.hh[6] = (bf16)((a1.z + b1.z) * linv);
  u.hh[7] = (bf16)((a1.w + b1.w) * linv);
  *(s16x4*)(ctx + base) = u.v[0];
  *(s16x4*)(ctx + base + 4) = u.v[1];
}

// out = fp32( hs + sigmoid(scale) * (ctx @ Wo^T) ), 128x64 tiles -> 512
// blocks (2/CU). v14 form (BK=32).
__global__ __launch_bounds__(256) void out_gemm(
    const bf16* __restrict__ ctx, const bf16* __restrict__ Wo,
    const float* __restrict__ hs, const float* __restrict__ scale_p,
    float* __restrict__ outp) {
  __shared__ bf16 ldsA[128 * 32];
  __shared__ bf16 ldsB[64 * 32];
  const int rowBase = blockIdx.y << 7, colBase = blockIdx.x << 6;
  const int t = threadIdx.x;
  const int w = t >> 6, l = t & 63;
  const int wr = (w >> 1) << 6, wc = (w & 1) << 5;  // wave tile 64x32
  const int lr = l & 15, lq = l >> 4;

  f32x4 acc[4][2];
  for (int mi = 0; mi < 4; mi++)
    for (int ni = 0; ni < 2; ni++)
      for (int r = 0; r < 4; r++) acc[mi][ni][r] = 0.f;

  const int sRow = (w << 4) + (l >> 2);
  const int sCol = (l & 3) << 3;
  const bf16* gA = ctx + (size_t)(rowBase + sRow) * HDIM + sCol;
  const bf16* gB = Wo + (size_t)(colBase + sRow) * HDIM + sCol;
  bf16* lA = ldsA + (w << 9);
  bf16* lB = ldsB + (w << 9);

  for (int k0 = 0; k0 < HDIM; k0 += 32) {
    glds16(gA, lA);
    glds16(gA + (size_t)64 * HDIM, lA + 2048);
    glds16(gB, lB);
    gA += 32; gB += 32;
    __syncthreads();

    bf16x8 af[4], bfr[2];
    for (int mi = 0; mi < 4; mi++)
      af[mi] = *(const bf16x8*)&ldsA[(wr + mi * 16 + lr) * 32 + lq * 8];
    for (int ni = 0; ni < 2; ni++)
      bfr[ni] = *(const bf16x8*)&ldsB[(wc + ni * 16 + lr) * 32 + lq * 8];
    for (int mi = 0; mi < 4; mi++)
      for (int ni = 0; ni < 2; ni++)
        acc[mi][ni] = MFMA16(af[mi], bfr[ni], acc[mi][ni]);
    __syncthreads();
  }

  const float sig = 1.0f / (1.0f + __expf(-scale_p[0]));
  for (int mi = 0; mi < 4; mi++)
    for (int ni = 0; ni < 2; ni++) {
      const int col = colBase + wc + ni * 16 + lr;
      const int row0 = rowBase + wr + mi * 16 + lq * 4;
      for (int r = 0; r < 4; r++) {
        const size_t idx = (size_t)(row0 + r) * HDIM + col;
        outp[idx] = hs[idx] + sig * acc[mi][ni][r];
      }
    }
}

extern "C" void kernel_launch(void* const* d_in, const int* in_sizes, int n_in,
                              void* d_out, int out_size, void* d_ws, size_t ws_size,
                              hipStream_t stream) {
  const float* hs = (const float*)d_in[0];
  const unsigned char* amask = (const unsigned char*)d_in[1];
  const float* Wq = (const float*)d_in[2];
  const float* Wk = (const float*)d_in[3];
  const float* Wv = (const float*)d_in[4];
  const float* Wo = (const float*)d_in[5];
  const float* scale_p = (const float*)d_in[6];
  float* outp = (float*)d_out;

  const size_t N = (size_t)HDIM * HDIM;  // 4M elems, 8MB bf16 each
  bf16* qb   = (bf16*)d_ws;
  bf16* Kf   = qb + N;
  bf16* Vf   = Kf + N;
  bf16* ctx  = Vf + N;
  bf16* hs16 = ctx + N;
  bf16* Wq16 = hs16 + N;
  bf16* Wk16 = Wq16 + N;
  bf16* Wv16 = Wk16 + N;
  bf16* Wo16 = Wv16 + N;   // 72 MB of d_ws
  // O partials (2 x 16MB f32) overlay hs16..Wv16 — dead after qkv_gemm.
  float* Of = (float*)hs16;
  // l partials (256KB) use d_out as scratch — overwritten later by out_gemm.
  float* lsumBuf = (float*)d_out;

  cvt5<<<dim3(1024, 5), 256, 0, stream>>>(hs, Wq, Wk, Wv, Wo,
                                          hs16, Wq16, Wk16, Wv16, Wo16);
  qkv_gemm<<<dim3(16, 16, 3), 256, 0, stream>>>(hs16, Wq16, Wk16, Wv16, qb, Kf, Vf);
  attn_kernel<<<dim3(8, 16, 2), 512, 0, stream>>>(qb, Kf, Vf, amask, Of, lsumBuf);
  combine_kernel<<<dim3(2048), 256, 0, stream>>>(Of, lsumBuf, ctx);
  out_gemm<<<dim3(32, 16), 256, 0, stream>>>(ctx, Wo16, hs, scale_p, outp);
}

// Round 14
// 275.786 us; speedup vs baseline: 1.0165x; 1.0165x over previous
//
#include <hip/hip_runtime.h>

typedef __bf16 bf16;
typedef __attribute__((ext_vector_type(8))) __bf16 bf16x8;
typedef __attribute__((ext_vector_type(4))) float f32x4;
typedef __attribute__((ext_vector_type(4))) short s16x4;

#define HDIM 2048

__device__ __forceinline__ void glds16(const void* g, void* l) {
  __builtin_amdgcn_global_load_lds((const __attribute__((address_space(1))) void*)g,
                                   (__attribute__((address_space(3))) void*)l,
                                   16, 0, 0);
}

#define MFMA16(a, b, c) __builtin_amdgcn_mfma_f32_16x16x32_bf16(a, b, c, 0, 0, 0)

// fp32 -> bf16 bulk convert: grid (1024, 5). BW-bound (~6 TB/s), done.
__global__ __launch_bounds__(256) void cvt5(
    const float* __restrict__ s0, const float* __restrict__ s1,
    const float* __restrict__ s2, const float* __restrict__ s3,
    const float* __restrict__ s4,
    bf16* __restrict__ d0, bf16* __restrict__ d1, bf16* __restrict__ d2,
    bf16* __restrict__ d3, bf16* __restrict__ d4) {
  const float* s; bf16* d;
  switch (blockIdx.y) {
    case 0: s = s0; d = d0; break;
    case 1: s = s1; d = d1; break;
    case 2: s = s2; d = d2; break;
    case 3: s = s3; d = d3; break;
    default: s = s4; d = d4; break;
  }
  const size_t base = (size_t)blockIdx.x * 4096 + (threadIdx.x << 2);
  for (int i = 0; i < 4; i++) {
    const float4 v = *(const float4*)(s + base + i * 1024);
    union { bf16 h[4]; s16x4 s4v; } u;
    u.h[0] = (bf16)v.x; u.h[1] = (bf16)v.y; u.h[2] = (bf16)v.z; u.h[3] = (bf16)v.w;
    *(s16x4*)(d + base + i * 1024) = u.s4v;
  }
}

// acc[4][4] = A[rowBase:+128, :] @ B[colBase:+128, :]^T, bf16 row-major.
// v14 form (m97 structure: glds16 width-16, BK=32, 4 waves 2x2) — the
// measured local optimum of this family at this shape: v15 (BK=64, fewer
// barrier domains), v16 (768-thread fusion, one barrier domain), v17
// (XCD swizzle, FETCH 45->102MB) all regressed with constant absolute
// MFMA/VALU cycles. The hiding mechanism is 3 co-resident blocks with
// INDEPENDENT barrier domains at different loop phases; default x-major
// dispatch already has near-ideal L2 behavior (45MB fetch vs 32MB ideal).
// 8-phase 256² is inapplicable here: 64 tiles/slice = 192 blocks on
// 256 CUs -> 1-block/CU single-domain exposure (the v9/v11/v16 mode).
__device__ __forceinline__ void gemm128_core(const bf16* __restrict__ A,
                                             const bf16* __restrict__ B,
                                             int rowBase, int colBase,
                                             f32x4 acc[4][4],
                                             bf16* ldsA, bf16* ldsB) {
  const int t = threadIdx.x;
  const int w = t >> 6, l = t & 63;
  const int wr = (w >> 1) << 6, wc = (w & 1) << 6;
  const int lr = l & 15, lq = l >> 4;

  for (int mi = 0; mi < 4; mi++)
    for (int ni = 0; ni < 4; ni++)
      for (int r = 0; r < 4; r++) acc[mi][ni][r] = 0.f;

  const int sRow = (w << 4) + (l >> 2);
  const int sCol = (l & 3) << 3;
  const bf16* gA = A + (size_t)(rowBase + sRow) * HDIM + sCol;
  const bf16* gB = B + (size_t)(colBase + sRow) * HDIM + sCol;
  bf16* lA = ldsA + (w << 9);
  bf16* lB = ldsB + (w << 9);

  for (int k0 = 0; k0 < HDIM; k0 += 32) {
    glds16(gA, lA);
    glds16(gA + (size_t)64 * HDIM, lA + 2048);
    glds16(gB, lB);
    glds16(gB + (size_t)64 * HDIM, lB + 2048);
    gA += 32; gB += 32;
    __syncthreads();

    bf16x8 af[4], bfr[4];
    for (int mi = 0; mi < 4; mi++)
      af[mi] = *(const bf16x8*)&ldsA[(wr + mi * 16 + lr) * 32 + lq * 8];
    for (int ni = 0; ni < 4; ni++)
      bfr[ni] = *(const bf16x8*)&ldsB[(wc + ni * 16 + lr) * 32 + lq * 8];
    for (int mi = 0; mi < 4; mi++)
      for (int ni = 0; ni < 4; ni++)
        acc[mi][ni] = MFMA16(af[mi], bfr[ni], acc[mi][ni]);
    __syncthreads();
  }
}

// z=0: q = hs@Wq^T (normal [B,H])
// z=1: Kf = hs@Wk^T re-tiled MFMA-B-frag-major (verified r4)
// z=2: Vf likewise. Plain blockIdx mapping (v17 swizzle reverted).
__global__ __launch_bounds__(256) void qkv_gemm(
    const bf16* __restrict__ hs, const bf16* __restrict__ Wq,
    const bf16* __restrict__ Wk, const bf16* __restrict__ Wv,
    bf16* __restrict__ qb, bf16* __restrict__ Kf, bf16* __restrict__ Vf) {
  __shared__ bf16 ldsA[128 * 32];
  __shared__ bf16 ldsB[128 * 32];
  const int z = blockIdx.z;
  const bf16* W = (z == 0) ? Wq : (z == 1) ? Wk : Wv;
  const int rowBase = blockIdx.y << 7, colBase = blockIdx.x << 7;
  f32x4 acc[4][4];
  gemm128_core(hs, W, rowBase, colBase, acc, ldsA, ldsB);

  const int t = threadIdx.x;
  const int w = t >> 6, l = t & 63;
  const int wr = (w >> 1) << 6, wc = (w & 1) << 6;
  const int lr = l & 15, lq = l >> 4;

  if (z == 0) {
    for (int mi = 0; mi < 4; mi++)
      for (int ni = 0; ni < 4; ni++) {
        const int col = colBase + wc + ni * 16 + lr;
        const int row0 = rowBase + wr + mi * 16 + lq * 4;
        for (int r = 0; r < 4; r++)
          qb[(size_t)(row0 + r) * HDIM + col] = (bf16)acc[mi][ni][r];
      }
  } else if (z == 1) {
    for (int mi = 0; mi < 4; mi++)
      for (int ni = 0; ni < 4; ni++) {
        const int dim = colBase + wc + ni * 16 + lr;
        const int hh = dim >> 7, ks = (dim >> 5) & 3, kh = (dim >> 3) & 3, j = dim & 7;
        const int row0 = rowBase + wr + mi * 16 + lq * 4;
        for (int r = 0; r < 4; r++) {
          const int key = row0 + r;
          const int kbk = key >> 7, kni = (key >> 4) & 7, kl = key & 15;
          Kf[(((size_t)hh * 16 + kbk) * 32 + kni * 4 + ks) * 512 +
             (kh * 16 + kl) * 8 + j] = (bf16)acc[mi][ni][r];
        }
      }
  } else {
    for (int mi = 0; mi < 4; mi++)
      for (int ni = 0; ni < 4; ni++) {
        const int dim = colBase + wc + ni * 16 + lr;
        const int hh = dim >> 7, vni = (dim >> 4) & 7, ll = dim & 15;
        const int row0 = rowBase + wr + mi * 16 + lq * 4;
        const int kbk = row0 >> 7, ks = (row0 >> 5) & 3, lh = (row0 >> 3) & 3;
        const int j0 = row0 & 7;  // r=0..3 contiguous in j
        union { bf16 h4[4]; s16x4 v; } u;
        for (int r = 0; r < 4; r++) u.h4[r] = (bf16)acc[mi][ni][r];
        *(s16x4*)&Vf[(((size_t)hh * 16 + kbk) * 32 + vni * 4 + ks) * 512 +
                     (lh * 16 + ll) * 8 + j0] = u.v;
      }
  }
}

// Flash attention v19 = v14 exact (measured best, 275.9us total).
// setprio REVERTED: 3-round ledger (v14 275.9 / v17 277.4 / v18 280.3
// with qkv equal) shows it null-to-harmful; the v17 "attn -4us" was
// cross-run noise (total noise band ±4us).
//  * 8-wave 512-thread block, grid (8 qt x 16 h x 2 kk) = 256 blocks,
//    2 waves/SIMD from block width.
//  * Double-buffered K AND V via glds16, m97-proven single-barrier pattern;
//    8 DMAs/wave/tile drained at the next barrier (depth <=8).
//  * 32 rows/wave; s[2][4] scoped per 64-key half; ~210 unified regs.
//  * LDS 160KB; 0-conflict P swizzle; kk-split partial O/l + combine.
__global__ __launch_bounds__(512, 2) void attn_kernel(
    const bf16* __restrict__ qb, const bf16* __restrict__ Kf,
    const bf16* __restrict__ Vf, const unsigned char* __restrict__ amask,
    float* __restrict__ Of, float* __restrict__ lsumBuf) {
  __shared__ bf16 Kl[2][32 * 512];  // 64KB
  __shared__ bf16 Vl[2][32 * 512];  // 64KB
  __shared__ bf16 Pl[8 * 32 * 64];  // 32KB (4KB/wave: 32 rows x 64 keys)

  const int qt = blockIdx.x, h = blockIdx.y, kk = blockIdx.z;
  const int t = threadIdx.x, w = t >> 6, l = t & 63;
  const int lr = l & 15, lq = l >> 4;
  bf16* Pw = Pl + (w << 11);  // 2048 elems per wave

  // Q A-frags (once): rows qt*256 + w*32 + mi*16 + lr, dims h*128 + ks*32 + lq*8
  bf16x8 aq[2][4];
  for (int mi = 0; mi < 2; mi++)
    for (int ks = 0; ks < 4; ks++)
      aq[mi][ks] = *(const bf16x8*)&qb[(size_t)(qt * 256 + w * 32 + mi * 16 + lr) * HDIM +
                                       h * 128 + ks * 32 + lq * 8];

  f32x4 o[2][8];
  for (int mi = 0; mi < 2; mi++)
    for (int ni = 0; ni < 8; ni++)
      for (int r = 0; r < 4; r++) o[mi][ni][r] = 0.f;
  float lsum[2][4];
  for (int mi = 0; mi < 2; mi++)
    for (int r = 0; r < 4; r++) lsum[mi][r] = 0.f;

  // exp2(s * c): c = 1/sqrt(128) * log2(e)
  const float c = 0.08838834764831845f * 1.4426950408889634f;

  const size_t headOff = (size_t)h * 16 * 32 * 512;
  // diag 128-key tile for this wave's 32 rows (wave-uniform)
  const int diagTile = qt * 2 + (w >> 2);

  // --- prologue: stage tile kk*8 into buf 0 (4 K + 4 V DMAs per wave) ---
  {
    const size_t t0 = headOff + (size_t)(kk * 8) * 32 * 512;
    for (int i = 0; i < 4; i++) {
      const int frag = i * 8 + w;
      glds16(Kf + t0 + frag * 512 + l * 8, &Kl[0][frag * 512]);
    }
    for (int i = 0; i < 4; i++) {
      const int frag = i * 8 + w;
      glds16(Vf + t0 + frag * 512 + l * 8, &Vl[0][frag * 512]);
    }
  }

  for (int tt = 0; tt < 8; tt++) {
    const int kbk = kk * 8 + tt;
    const int buf = tt & 1;

    // barrier: drains tile-t DMAs; all waves past tile t-1's reads of
    // buf^1 -> safe to refill it.
    __syncthreads();

    if (tt < 7) {
      const size_t tN = headOff + (size_t)(kbk + 1) * 32 * 512;
      for (int i = 0; i < 4; i++) {
        const int frag = i * 8 + w;
        glds16(Kf + tN + frag * 512 + l * 8, &Kl[buf ^ 1][frag * 512]);
      }
      for (int i = 0; i < 4; i++) {
        const int frag = i * 8 + w;
        glds16(Vf + tN + frag * 512 + l * 8, &Vl[buf ^ 1][frag * 512]);
      }
    }

    for (int half = 0; half < 2; half++) {
      // --- S = Q @ K^T for this 64-key half (s scoped -> dies per half) ---
      f32x4 s[2][4];
      for (int mi = 0; mi < 2; mi++)
        for (int ni = 0; ni < 4; ni++)
          for (int r = 0; r < 4; r++) s[mi][ni][r] = 0.f;
      for (int ks = 0; ks < 4; ks++) {
        bf16x8 bk[4];
        for (int ni = 0; ni < 4; ni++)
          bk[ni] = *(const bf16x8*)&Kl[buf][((half * 4 + ni) * 4 + ks) * 512 + l * 8];
        for (int ni = 0; ni < 4; ni++) {
          s[0][ni] = MFMA16(aq[0][ks], bk[ni], s[0][ni]);
          s[1][ni] = MFMA16(aq[1][ks], bk[ni], s[1][ni]);
        }
      }

      // --- softmax: additive mask; diag tile uniform per wave ---
      float am[4];
      for (int ni = 0; ni < 4; ni++)
        am[ni] = amask[kbk * 128 + half * 64 + ni * 16 + lr] ? 0.f : -1e30f;
      if (kbk == diagTile) {
        for (int mi = 0; mi < 2; mi++)
          for (int ni = 0; ni < 4; ni++) {
            const int colL = half * 64 + ni * 16 + lr;
            for (int r = 0; r < 4; r++) {
              const int rowL = (w & 3) * 32 + mi * 16 + lq * 4 + r;
              float p = __builtin_exp2f(s[mi][ni][r] * c + am[ni]);
              if (colL == rowL) p = 0.f;
              s[mi][ni][r] = p;
              lsum[mi][r] += p;
            }
          }
      } else {
        for (int mi = 0; mi < 2; mi++)
          for (int ni = 0; ni < 4; ni++)
            for (int r = 0; r < 4; r++) {
              const float p = __builtin_exp2f(s[mi][ni][r] * c + am[ni]);
              s[mi][ni][r] = p;
              lsum[mi][r] += p;
            }
      }

      // --- P write (0-conflict swizzle, 64-key rows; v10/v12-verified) ---
      for (int mi = 0; mi < 2; mi++)
        for (int ni = 0; ni < 4; ni++)
          for (int r = 0; r < 4; r++) {
            const int rl = lq * 4 + r;
            Pw[(mi * 16 + rl) * 64 + (((ni * 2 + (lr >> 3)) ^ (rl & 7)) << 3) +
               (lr & 7)] = (bf16)s[mi][ni][r];
          }

      // --- PV for this half: V k-slices half*2, half*2+1 ---
      for (int ksp = 0; ksp < 2; ksp++) {
        bf16x8 bv[8];
        for (int ni = 0; ni < 8; ni++)
          bv[ni] = *(const bf16x8*)&Vl[buf][(ni * 4 + half * 2 + ksp) * 512 + l * 8];
        const int rchunk = ((ksp * 4 + lq) ^ (lr & 7)) << 3;
        const bf16x8 ap0 = *(const bf16x8*)&Pw[lr * 64 + rchunk];
        const bf16x8 ap1 = *(const bf16x8*)&Pw[(16 + lr) * 64 + rchunk];
        for (int ni = 0; ni < 8; ni++) {
          o[0][ni] = MFMA16(ap0, bv[ni], o[0][ni]);
          o[1][ni] = MFMA16(ap1, bv[ni], o[1][ni]);
        }
      }
    }
  }

  // --- per-wave l reduction: butterfly over the 16 key-lanes ---
  for (int mi = 0; mi < 2; mi++)
    for (int r = 0; r < 4; r++)
      for (int off = 1; off < 16; off <<= 1)
        lsum[mi][r] += __shfl_xor(lsum[mi][r], off);

  // --- epilogue: write f32 partial O and partial l (no division here) ---
  const size_t obase = (size_t)kk * ((size_t)HDIM * HDIM);
  for (int mi = 0; mi < 2; mi++)
    for (int ni = 0; ni < 8; ni++)
      for (int r = 0; r < 4; r++) {
        const int row = qt * 256 + w * 32 + mi * 16 + lq * 4 + r;
        const int col = h * 128 + ni * 16 + lr;
        Of[obase + (size_t)row * HDIM + col] = o[mi][ni][r];
      }
  if (lr == 0)
    for (int mi = 0; mi < 2; mi++)
      for (int r = 0; r < 4; r++) {
        const int row = qt * 256 + w * 32 + mi * 16 + lq * 4 + r;
        lsumBuf[((size_t)kk * 16 + h) * 2048 + row] = lsum[mi][r];
      }
}

// ctx = bf16( (O0+O1) / (l0+l1) ), fully-masked rows -> 0.  Grid 2048x256,
// 8 elems/thread (one row per block). Of traffic is L2/L3-resident.
__global__ __launch_bounds__(256) void combine_kernel(
    const float* __restrict__ Of, const float* __restrict__ lsumBuf,
    bf16* __restrict__ ctx) {
  const size_t base = (size_t)blockIdx.x * 2048 + ((size_t)threadIdx.x << 3);
  const int row = (int)(base >> 11);
  const int h = ((int)base & 2047) >> 7;
  const float lt = lsumBuf[h * 2048 + row] + lsumBuf[(16 + h) * 2048 + row];
  const float linv = (lt > 0.f) ? 1.f / lt : 0.f;
  const float* p0 = Of + base;
  const float* p1 = Of + (size_t)4194304 + base;
  const float4 a0 = *(const float4*)p0;
  const float4 a1 = *(const float4*)(p0 + 4);
  const float4 b0 = *(const float4*)p1;
  const float4 b1 = *(const float4*)(p1 + 4);
  union { bf16 hh[8]; s16x4 v[2]; } u;
  u.hh[0] = (bf16)((a0.x + b0.x) * linv);
  u.hh[1] = (bf16)((a0.y + b0.y) * linv);
  u.hh[2] = (bf16)((a0.z + b0.z) * linv);
  u.hh[3] = (bf16)((a0.w + b0.w) * linv);
  u.hh[4] = (bf16)((a1.x + b1.x) * linv);
  u.hh[5] = (bf16)((a1.y + b1.y) * linv);
  u.hh[6] = (bf16)((a1.z + b1.z) * linv);
  u.hh[7] = (bf16)((a1.w + b1.w) * linv);
  *(s16x4*)(ctx + base) = u.v[0];
  *(s16x4*)(ctx + base + 4) = u.v[1];
}

// out = fp32( hs + sigmoid(scale) * (ctx @ Wo^T) ), 128x64 tiles -> 512
// blocks (2/CU). v14 form (BK=32).
__global__ __launch_bounds__(256) void out_gemm(
    const bf16* __restrict__ ctx, const bf16* __restrict__ Wo,
    const float* __restrict__ hs, const float* __restrict__ scale_p,
    float* __restrict__ outp) {
  __shared__ bf16 ldsA[128 * 32];
  __shared__ bf16 ldsB[64 * 32];
  const int rowBase = blockIdx.y << 7, colBase = blockIdx.x << 6;
  const int t = threadIdx.x;
  const int w = t >> 6, l = t & 63;
  const int wr = (w >> 1) << 6, wc = (w & 1) << 5;  // wave tile 64x32
  const int lr = l & 15, lq = l >> 4;

  f32x4 acc[4][2];
  for (int mi = 0; mi < 4; mi++)
    for (int ni = 0; ni < 2; ni++)
      for (int r = 0; r < 4; r++) acc[mi][ni][r] = 0.f;

  const int sRow = (w << 4) + (l >> 2);
  const int sCol = (l & 3) << 3;
  const bf16* gA = ctx + (size_t)(rowBase + sRow) * HDIM + sCol;
  const bf16* gB = Wo + (size_t)(colBase + sRow) * HDIM + sCol;
  bf16* lA = ldsA + (w << 9);
  bf16* lB = ldsB + (w << 9);

  for (int k0 = 0; k0 < HDIM; k0 += 32) {
    glds16(gA, lA);
    glds16(gA + (size_t)64 * HDIM, lA + 2048);
    glds16(gB, lB);
    gA += 32; gB += 32;
    __syncthreads();

    bf16x8 af[4], bfr[2];
    for (int mi = 0; mi < 4; mi++)
      af[mi] = *(const bf16x8*)&ldsA[(wr + mi * 16 + lr) * 32 + lq * 8];
    for (int ni = 0; ni < 2; ni++)
      bfr[ni] = *(const bf16x8*)&ldsB[(wc + ni * 16 + lr) * 32 + lq * 8];
    for (int mi = 0; mi < 4; mi++)
      for (int ni = 0; ni < 2; ni++)
        acc[mi][ni] = MFMA16(af[mi], bfr[ni], acc[mi][ni]);
    __syncthreads();
  }

  const float sig = 1.0f / (1.0f + __expf(-scale_p[0]));
  for (int mi = 0; mi < 4; mi++)
    for (int ni = 0; ni < 2; ni++) {
      const int col = colBase + wc + ni * 16 + lr;
      const int row0 = rowBase + wr + mi * 16 + lq * 4;
      for (int r = 0; r < 4; r++) {
        const size_t idx = (size_t)(row0 + r) * HDIM + col;
        outp[idx] = hs[idx] + sig * acc[mi][ni][r];
      }
    }
}

extern "C" void kernel_launch(void* const* d_in, const int* in_sizes, int n_in,
                              void* d_out, int out_size, void* d_ws, size_t ws_size,
                              hipStream_t stream) {
  const float* hs = (const float*)d_in[0];
  const unsigned char* amask = (const unsigned char*)d_in[1];
  const float* Wq = (const float*)d_in[2];
  const float* Wk = (const float*)d_in[3];
  const float* Wv = (const float*)d_in[4];
  const float* Wo = (const float*)d_in[5];
  const float* scale_p = (const float*)d_in[6];
  float* outp = (float*)d_out;

  const size_t N = (size_t)HDIM * HDIM;  // 4M elems, 8MB bf16 each
  bf16* qb   = (bf16*)d_ws;
  bf16* Kf   = qb + N;
  bf16* Vf   = Kf + N;
  bf16* ctx  = Vf + N;
  bf16* hs16 = ctx + N;
  bf16* Wq16 = hs16 + N;
  bf16* Wk16 = Wq16 + N;
  bf16* Wv16 = Wk16 + N;
  bf16* Wo16 = Wv16 + N;   // 72 MB of d_ws
  // O partials (2 x 16MB f32) overlay hs16..Wv16 — dead after qkv_gemm.
  float* Of = (float*)hs16;
  // l partials (256KB) use d_out as scratch — overwritten later by out_gemm.
  float* lsumBuf = (float*)d_out;

  cvt5<<<dim3(1024, 5), 256, 0, stream>>>(hs, Wq, Wk, Wv, Wo,
                                          hs16, Wq16, Wk16, Wv16, Wo16);
  qkv_gemm<<<dim3(16, 16, 3), 256, 0, stream>>>(hs16, Wq16, Wk16, Wv16, qb, Kf, Vf);
  attn_kernel<<<dim3(8, 16, 2), 512, 0, stream>>>(qb, Kf, Vf, amask, Of, lsumBuf);
  combine_kernel<<<dim3(2048), 256, 0, stream>>>(Of, lsumBuf, ctx);
  out_gemm<<<dim3(32, 16), 256, 0, stream>>>(ctx, Wo16, hs, scale_p, outp);
}